// Round 5
// baseline (210.600 us; speedup 1.0000x reference)
//
#include <hip/hip_runtime.h>

#define NPG  256   // nodes per graph
#define EPG  4096  // edges per graph
#define FDIM 128
#define KTOP 30

// 512 threads/block = 8 waves = 2 waves/SIMD. Thread pair (t, t+256) shares
// node n = t&255: role A (half=0) owns output channels 0..15, role B 16..31.
// Pairing across waves keeps every W-row read wave-uniform -> scalar loads.
//
// Rounds 1-4 lesson: the backend pins the VGPR budget at 128 for this
// 512-thread/55.8KB-LDS shape no matter what __launch_bounds__ /
// amdgpu_waves_per_eu says (VGPR_Count==128 in 4/4 rounds), and spills the
// overflow to scratch (15-60 MB/dispatch of HBM traffic = the runtime).
// So this version is restructured to need ~60 live VGPRs:
//  - phase 0 column-split: acc[16], pair redundantly reads the row (L2-hit)
//  - matml via LDS-staged h: a[16], partner half read from own Ybuf row
//  - layer-3 y3 lives in the spare col 32 of the stride-33 row
__global__ __launch_bounds__(512)
__attribute__((amdgpu_waves_per_eu(2, 2)))
void dgcnn_fused(const float* __restrict__ node_feat,
                 const int* __restrict__ srcv, const int* __restrict__ dstv,
                 const int* __restrict__ degs,
                 const float* __restrict__ W0, const float* __restrict__ b0,
                 const float* __restrict__ W1, const float* __restrict__ b1,
                 const float* __restrict__ W2, const float* __restrict__ b2,
                 const float* __restrict__ W3, const float* __restrict__ b3,
                 const float* __restrict__ cw1, const float* __restrict__ cb1,
                 const float* __restrict__ cw2, const float* __restrict__ cb2,
                 const float* __restrict__ ow,  const float* __restrict__ ob,
                 float* __restrict__ outp)
{
    __shared__ float Ybuf[NPG * 33];   // 33792 B; stride 33; col 32 spare for y3
    __shared__ int   srclist[EPG];     // 16384 B; in-edges grouped by dst; reused by tail
    __shared__ int   offs[NPG];
    __shared__ int   cnt [NPG];
    __shared__ int   degl[NPG];
    __shared__ float invd[NPG];
    __shared__ float keys[NPG];
    __shared__ int   wsum[4];
    // total ~55.3 KB

    const int g    = blockIdx.x;
    const int t    = threadIdx.x;
    const int n    = t & (NPG - 1);
    const int half = t >> 8;          // 0: channels 0..15, 1: channels 16..31
    const int co   = half * 16;
    const int oco  = co ^ 16;         // partner's channel base

    // ================= degrees + wave-shuffle prefix scan (2 barriers) =======
    const int dn = degs[g * NPG + n];
    if (half == 0) {
        degl[n] = dn;
        cnt[n]  = 0;
        invd[n] = 1.0f / (float)(dn + 1);
    }
    {
        int v = (half == 0) ? dn : 0;
        const int lane = t & 63;
        #pragma unroll
        for (int off = 1; off < 64; off <<= 1) {
            int u = __shfl_up(v, off);
            if (lane >= off) v += u;
        }
        if (half == 0 && lane == 63) wsum[t >> 6] = v;   // wave totals (waves 0..3)
        __syncthreads();
        if (half == 0) {
            const int w = t >> 6;
            int base = 0;
            #pragma unroll
            for (int i = 0; i < 4; i++) base += (i < w) ? wsum[i] : 0;
            offs[n] = base + v - dn;   // exclusive prefix of in-degrees
        }
        __syncthreads();
    }

    // ================= edge-list build (counting sort by dst) ================
    {
        const int* sg = srcv + g * EPG;
        const int* dg = dstv + g * EPG;
        #pragma unroll
        for (int i = 0; i < EPG / 512; i++) {
            int e  = t + i * 512;
            int ss = sg[e] & (NPG - 1);   // graphs are 256-node aligned
            int dd = dg[e] & (NPG - 1);
            int p  = atomicAdd(&cnt[dd], 1);
            srclist[offs[dd] + p] = ss;
        }
    }

    // ================= phase 0: y0 = node_feat @ W0 (column-split) ===========
    // Thread computes cols co..co+15 over all 128 k. acc[16] + 4 float4 in
    // flight ~ 45 live VGPRs. Pair threads read the same row: L1/L2 absorbs.
    {
        const float4* nf4 = (const float4*)(node_feat + ((size_t)g * NPG + n) * FDIM);
        float acc[16];
        #pragma unroll
        for (int c = 0; c < 16; c++) acc[c] = 0.f;
        #pragma unroll 4
        for (int q = 0; q < 32; q++) {
            const float4 r = nf4[q];
            const float* w0 = W0 + (q * 4 + 0) * 32 + co;   // wave-uniform -> scalar
            const float* w1 = W0 + (q * 4 + 1) * 32 + co;
            const float* w2 = W0 + (q * 4 + 2) * 32 + co;
            const float* w3 = W0 + (q * 4 + 3) * 32 + co;
            #pragma unroll
            for (int c = 0; c < 16; c++) {
                float a = acc[c];
                a = fmaf(r.x, w0[c], a);
                a = fmaf(r.y, w1[c], a);
                a = fmaf(r.z, w2[c], a);
                a = fmaf(r.w, w3[c], a);
                acc[c] = a;
            }
        }
        #pragma unroll
        for (int c = 0; c < 16; c++) Ybuf[n * 33 + co + c] = acc[c];
        __syncthreads();   // y0 visible + edge build complete
    }

    const float iv = invd[n];
    const int   o  = offs[n];
    const int   d  = degl[n];

    // pooled (my 16-channel half) = y[n] + sum_{in-edges} y[src]
    auto agg16 = [&](float (&h)[16]) {
        const float* self = &Ybuf[n * 33 + co];
        #pragma unroll
        for (int c = 0; c < 16; c++) h[c] = self[c];
        for (int j = 0; j < d; j++) {
            const float* yr = &Ybuf[srclist[o + j] * 33 + co];
            #pragma unroll
            for (int c = 0; c < 16; c++) h[c] += yr[c];
        }
    };
    auto act16 = [&](float (&h)[16], const float* bb) {
        #pragma unroll
        for (int c = 0; c < 16; c++) h[c] = tanhf((h[c] + bb[co + c]) * iv);
    };
    auto store_h = [&](const float (&h)[16]) {
        #pragma unroll
        for (int c = 0; c < 16; c++) Ybuf[n * 33 + co + c] = h[c];
    };
    // y_next cols co..co+15 = h(full row) @ Wn. Own half from registers,
    // partner half from own Ybuf row (bank-free: fixed col, consecutive n).
    auto matml16 = [&](const float (&h)[16], const float* Wn) {
        float a[16];
        #pragma unroll
        for (int c = 0; c < 16; c++) a[c] = 0.f;
        #pragma unroll
        for (int kk = 0; kk < 16; kk++) {
            const float* wr = Wn + (co + kk) * 32 + co;   // wave-uniform -> scalar
            const float  hk = h[kk];
            #pragma unroll
            for (int c = 0; c < 16; c++) a[c] = fmaf(hk, wr[c], a[c]);
        }
        #pragma unroll
        for (int kk = 0; kk < 16; kk++) {
            const float* wr = Wn + (oco + kk) * 32 + co;
            const float  hk = Ybuf[n * 33 + oco + kk];
            #pragma unroll
            for (int c = 0; c < 16; c++) a[c] = fmaf(hk, wr[c], a[c]);
        }
        __syncthreads();   // all h reads (incl. partner's of my cols) done
        #pragma unroll
        for (int c = 0; c < 16; c++) Ybuf[n * 33 + co + c] = a[c];
        __syncthreads();   // y_next visible
    };

    // ================= 4 GNN layers =================
    float h1[16], h2[16], h3[16];
    agg16(h1); act16(h1, b0);
    __syncthreads();       // agg reads of y0 done
    store_h(h1);
    __syncthreads();       // h1 visible
    matml16(h1, W1);

    agg16(h2); act16(h2, b1);
    __syncthreads();
    store_h(h2);
    __syncthreads();
    matml16(h2, W2);

    agg16(h3); act16(h3, b2);
    __syncthreads();
    store_h(h3);
    __syncthreads();
    float kv;
    {   // layer 3 projection: y3 = h3(full) @ W3 (32x1) -> spare col 32
        float a3 = 0.f;
        #pragma unroll
        for (int kk = 0; kk < 16; kk++) a3 = fmaf(h3[kk], W3[co + kk], a3);
        #pragma unroll
        for (int kk = 0; kk < 16; kk++) a3 = fmaf(Ybuf[n * 33 + oco + kk], W3[oco + kk], a3);
        if (half == 0) Ybuf[n * 33 + 32] = a3;   // col 32: doesn't clobber h3
        __syncthreads();   // y3 visible
        // layer 3 aggregate (1-wide) + activation -> sort key
        float s = Ybuf[n * 33 + 32];
        for (int j = 0; j < d; j++) s += Ybuf[srclist[o + j] * 33 + 32];
        kv = tanhf((s + b3[0]) * iv);
        if (half == 0) keys[n] = kv;
    }
    __syncthreads();

    // ================= sortpool: rank-based top-K (jax tie-break: lower idx) ==
    int rank = 0;
    #pragma unroll 4
    for (int j = 0; j < NPG; j++) {
        float vj = keys[j];
        rank += ((vj > kv) || ((vj == kv) && (j < n))) ? 1 : 0;
    }

    // ================= export selected Z rows, then conv tail ================
    float* sp    = (float*)srclist;   // 2910 floats (srclist dead from here)
    float* x1    = sp + 30 * 97;      // 480
    float* xp    = x1 + 480;          // 240
    float* dense = xp + 240;          // 352  (total 3982 floats <= 4096)

    if (rank < KTOP) {
        float* dp = sp + rank * 97 + co;
        #pragma unroll
        for (int c = 0; c < 16; c++) dp[c]      = h1[c];
        #pragma unroll
        for (int c = 0; c < 16; c++) dp[32 + c] = h2[c];
        #pragma unroll
        for (int c = 0; c < 16; c++) dp[64 + c] = h3[c];
        if (half == 0) sp[rank * 97 + 96] = kv;
    }
    __syncthreads();

    // conv1: kernel width 97, stride 97 -> per-row dot; out [16][30], relu
    for (int idx = t; idx < 480; idx += 512) {
        int k = idx >> 4, c = idx & 15;
        float s = cb1[c];
        for (int dd = 0; dd < 97; dd++) s = fmaf(sp[k * 97 + dd], cw1[c * 97 + dd], s);
        x1[c * 30 + k] = fmaxf(s, 0.f);
    }
    __syncthreads();
    // maxpool1d(2,2) -> [16][15]
    for (int idx = t; idx < 240; idx += 512) {
        int c = idx / 15, k = idx - c * 15;
        xp[idx] = fmaxf(x1[c * 30 + 2 * k], x1[c * 30 + 2 * k + 1]);
    }
    __syncthreads();
    // conv2: [32][16][5] VALID over 15 -> [32][11], relu; dense idx = c*11+j
    for (int idx = t; idx < 352; idx += 512) {
        int c = idx / 11, j = idx - c * 11;
        float s = cb2[c];
        for (int i2 = 0; i2 < 16; i2++) {
            #pragma unroll
            for (int tt = 0; tt < 5; tt++)
                s = fmaf(xp[i2 * 15 + j + tt], cw2[(c * 16 + i2) * 5 + tt], s);
        }
        dense[idx] = fmaxf(s, 0.f);
    }
    __syncthreads();
    // output: relu(relu(dense @ out_w + out_b)) -> [2]
    if (t < 64) {
        float a0 = 0.f, a1 = 0.f;
        for (int dd = t; dd < 352; dd += 64) {
            float v = dense[dd];
            a0 = fmaf(v, ow[dd * 2],     a0);
            a1 = fmaf(v, ow[dd * 2 + 1], a1);
        }
        #pragma unroll
        for (int off2 = 32; off2 > 0; off2 >>= 1) {
            a0 += __shfl_down(a0, off2);
            a1 += __shfl_down(a1, off2);
        }
        if (t == 0) {
            outp[g * 2 + 0] = fmaxf(a0 + ob[0], 0.f);
            outp[g * 2 + 1] = fmaxf(a1 + ob[1], 0.f);
        }
    }
}

extern "C" void kernel_launch(void* const* d_in, const int* in_sizes, int n_in,
                              void* d_out, int out_size, void* d_ws, size_t ws_size,
                              hipStream_t stream) {
    const float* node_feat = (const float*)d_in[0];
    const int*   src       = (const int*)  d_in[1];
    const int*   dst       = (const int*)  d_in[2];
    const int*   degsp     = (const int*)  d_in[3];
    const float* W0 = (const float*)d_in[4];
    const float* b0 = (const float*)d_in[5];
    const float* W1 = (const float*)d_in[6];
    const float* b1 = (const float*)d_in[7];
    const float* W2 = (const float*)d_in[8];
    const float* b2 = (const float*)d_in[9];
    const float* W3 = (const float*)d_in[10];
    const float* b3 = (const float*)d_in[11];
    const float* cw1 = (const float*)d_in[12];
    const float* cb1 = (const float*)d_in[13];
    const float* cw2 = (const float*)d_in[14];
    const float* cb2 = (const float*)d_in[15];
    const float* ow  = (const float*)d_in[16];
    const float* ob  = (const float*)d_in[17];

    dgcnn_fused<<<dim3(256), dim3(512), 0, stream>>>(
        node_feat, src, dst, degsp,
        W0, b0, W1, b1, W2, b2, W3, b3,
        cw1, cb1, cw2, cb2, ow, ob, (float*)d_out);
}